// Round 19
// baseline (151.276 us; speedup 1.0000x reference)
//
#include <hip/hip_runtime.h>
#include <stdint.h>

#define NUM_HEADS 12
#define DH 64
#define SEQ 2048
#define BATCH 2
#define DM 768
#define NQK 1536  // Q cols [0,768) | K cols [768,1536)
#define LOG2E 1.44269504088896340736f

typedef short short8 __attribute__((ext_vector_type(8)));
typedef short short4_t __attribute__((ext_vector_type(4)));
typedef float f32x4 __attribute__((ext_vector_type(4)));
typedef unsigned long long u64;

__device__ __forceinline__ short bf16_rne(float f) {
    union { float f; uint32_t u; } v; v.f = f;
    return (short)((v.u + 0x7FFFu + ((v.u >> 16) & 1u)) >> 16);
}

// async global->LDS, 16B per lane; LDS dest = wave-uniform base + lane*16 (linear)
#define GLOAD_LDS(gp, lp)                                                          \
    __builtin_amdgcn_global_load_lds(                                              \
        (const __attribute__((address_space(1))) void*)(gp),                       \
        (__attribute__((address_space(3))) void*)(lp), 16, 0, 0)

// ---------------- Kernel 0: prep (wt | xb | mpack), branch on blockIdx ----------------
__global__ __launch_bounds__(256) void prep_kernel(const float* __restrict__ Wq,
                                                   const float* __restrict__ Wk,
                                                   const float* __restrict__ x,
                                                   const int* __restrict__ mask,
                                                   short* __restrict__ Wt,
                                                   short* __restrict__ Xb,
                                                   u64* __restrict__ Mb) {
    __shared__ float tile[32][33];
    const int bid = blockIdx.x;
    const int t = threadIdx.x;
    if (bid < 1152) {
        int n0 = (bid % 48) * 32;
        int k0 = (bid / 48) * 32;
        int tx = t & 31;
        int ty = t >> 5;
        const float* src = (n0 < DM) ? Wq : Wk;
        int nn0 = (n0 < DM) ? n0 : n0 - DM;
#pragma unroll
        for (int j = 0; j < 4; ++j) {
            int k = ty + 8 * j;
            tile[k][tx] = src[(size_t)(k0 + k) * DM + nn0 + tx];
        }
        __syncthreads();
#pragma unroll
        for (int j = 0; j < 4; ++j) {
            int n = ty + 8 * j;
            Wt[(size_t)(n0 + n) * DM + k0 + tx] = bf16_rne(tile[tx][n]);
        }
    } else if (bid < 1920) {
        // ---- xb: x -> bf16 ----
        size_t base = (size_t)(bid - 1152) * 4096;
#pragma unroll
        for (int j = 0; j < 4; ++j) {
            size_t i = base + (size_t)(t + j * 256) * 4;
            f32x4 v = *(const f32x4*)(x + i);
            short4_t s;
#pragma unroll
            for (int e = 0; e < 4; ++e) s[e] = bf16_rne(v[e]);
            *(short4_t*)(Xb + i) = s;
        }
    } else {
        // ---- mpack ----
        int wid = (bid - 1920) * 4 + (t >> 6);
        int lane = t & 63;
        size_t base = (size_t)wid * 8;
#pragma unroll
        for (int i = 0; i < 8; ++i) {
            size_t w = base + i;
            int v = mask[w * 64 + lane];
            u64 bal = __ballot(v != 0);
            if (lane == 0) Mb[w] = bal;
        }
    }
}

// ---------------- Kernel 1: proj GEMM (128x128, BK=64), global_load_lds staging ----------------
__global__ __launch_bounds__(256) void proj_kernel(const short* __restrict__ Xb,
                                                   const short* __restrict__ Wt,
                                                   const float* __restrict__ bq,
                                                   const float* __restrict__ bk,
                                                   short* __restrict__ QK) {
    __shared__ short As[128 * 64];  // 16 KB
    __shared__ short Bs[128 * 64];  // 16 KB
    const int m0 = blockIdx.x * 128;
    const int n0 = blockIdx.y * 128;
    const int t = threadIdx.x;
    const int lane = t & 63;
    const int w = t >> 6;
    const int wr = w >> 1, wc = w & 1;
    const int lr = lane & 15;
    const int lk = lane >> 4;
    const int crow = lane >> 3;            // row within 8-row chunk
    const int cc = (lane & 7) ^ crow;      // swizzled source 16B-chunk index
    const int xr = (lr & 7) << 4;          // read-side XOR (row&7)<<4 bytes

    f32x4 acc[4][4] = {};

    for (int k0 = 0; k0 < DM; k0 += 64) {
#pragma unroll
        for (int i = 0; i < 4; ++i) {
            int ci = w * 4 + i;            // 16 chunks of 8 rows x 1KB
            int row = ci * 8 + crow;
            GLOAD_LDS(&Xb[(size_t)(m0 + row) * DM + k0 + cc * 8], &As[ci * 512]);
            GLOAD_LDS(&Wt[(size_t)(n0 + row) * DM + k0 + cc * 8], &Bs[ci * 512]);
        }
        __syncthreads();
#pragma unroll
        for (int kk = 0; kk < 2; ++kk) {
            short8 a[4], bfr[4];
#pragma unroll
            for (int m = 0; m < 4; ++m) {
                int row = wr * 64 + m * 16 + lr;
                a[m] = *(short8*)((char*)As + row * 128 + ((kk * 64 + lk * 16) ^ xr));
            }
#pragma unroll
            for (int n = 0; n < 4; ++n) {
                int row = wc * 64 + n * 16 + lr;
                bfr[n] = *(short8*)((char*)Bs + row * 128 + ((kk * 64 + lk * 16) ^ xr));
            }
#pragma unroll
            for (int m = 0; m < 4; ++m)
#pragma unroll
                for (int n = 0; n < 4; ++n)
                    acc[m][n] = __builtin_amdgcn_mfma_f32_16x16x32_bf16(a[m], bfr[n], acc[m][n], 0, 0, 0);
        }
        __syncthreads();
    }

    const int orow = m0 + wr * 64;
    const int ocol = n0 + wc * 64;
#pragma unroll
    for (int m = 0; m < 4; ++m) {
#pragma unroll
        for (int n = 0; n < 4; ++n) {
            int col = ocol + n * 16 + lr;
            float bias = (col < DM) ? bq[col] : bk[col - DM];
            float scale = (col < DM) ? 0.125f * LOG2E : 1.0f;
#pragma unroll
            for (int r = 0; r < 4; ++r) {
                int row = orow + m * 16 + lk * 4 + r;
                QK[(size_t)row * NQK + col] = bf16_rne((acc[m][n][r] + bias) * scale);
            }
        }
    }
}

// ---------------- Kernel 2: attn (R18 + counted-vmcnt raw-barrier pipeline in pass B) ----------------
__global__ __launch_bounds__(256) void attn_kernel(const short* __restrict__ QK,
                                                   const u64* __restrict__ Mb,
                                                   float* __restrict__ out) {
    __shared__ short Ks[2][64 * 64];   // 16 KB (linear, swizzled)
    __shared__ float Pb[64 * 132];     // 33.8 KB
    const int bid = blockIdx.x;
    const int xcd = bid & 7;
    const int jj = bid >> 3;
    const int bh = xcd * 3 + (jj >> 5);
    const int qblk = jj & 31;
    const int b = bh / NUM_HEADS;
    const int h = bh % NUM_HEADS;
    const int t = threadIdx.x;
    const int lane = t & 63;
    const int w = t >> 6;
    const int lr = lane & 15;
    const int lk = lane >> 4;
    const int wq = qblk * 64 + w * 16;
    const int crow = lane >> 3;            // row within 8-row region
    const int cc = (lane & 7) ^ crow;      // swizzled source chunk
    const int xr = (lr & 7) << 4;          // read-side XOR

    short8 aq[2];
#pragma unroll
    for (int ks = 0; ks < 2; ++ks)
        aq[ks] = *(const short8*)&QK[(size_t)(b * SEQ + wq + lr) * NQK + h * DH + ks * 32 + lk * 8];

    float lrow[4] = {0.f, 0.f, 0.f, 0.f};
    const size_t mrow0 = (size_t)b * SEQ * 32;

    // stage 128 keys: 16 regions of 8 rows x 1KB; wave w handles regions w*4..w*4+3
#define ATT_STAGE(KT)                                                                             \
    {                                                                                             \
        _Pragma("unroll") for (int i = 0; i < 4; ++i) {                                           \
            int ci = w * 4 + i;                                                                   \
            int tile = ci >> 3;                                                                   \
            int reg = ci & 7;                                                                     \
            int row = reg * 8 + crow;                                                             \
            GLOAD_LDS(&QK[(size_t)(b * SEQ + (KT) + tile * 64 + row) * NQK + DM + h * DH +        \
                          cc * 8],                                                                \
                      &Ks[tile][reg * 512]);                                                      \
        }                                                                                         \
    }

#define K_READ(TB, NF, OFS)                                                                       \
    (*(short8*)((char*)&Ks[TB][0] + ((NF) * 16 + lr) * 128 + (((OFS) + lk * 16) ^ xr)))

    // ---- pass A: masked sum of exp2 (unchanged sync structure) ----
    for (int kt = 0; kt < SEQ; kt += 128) {
        ATT_STAGE(kt)
        __syncthreads();
#pragma unroll
        for (int tb = 0; tb < 2; ++tb) {
            f32x4 sc[4];
#pragma unroll
            for (int nf = 0; nf < 4; ++nf) {
                short8 k0 = K_READ(tb, nf, 0);
                short8 k1 = K_READ(tb, nf, 64);
                f32x4 a = {0.f, 0.f, 0.f, 0.f};
                a = __builtin_amdgcn_mfma_f32_16x16x32_bf16(aq[0], k0, a, 0, 0, 0);
                a = __builtin_amdgcn_mfma_f32_16x16x32_bf16(aq[1], k1, a, 0, 0, 0);
                sc[nf] = a;
            }
#pragma unroll
            for (int r = 0; r < 4; ++r) {
                int q = wq + lk * 4 + r;
                u64 mbs = Mb[mrow0 + (size_t)q * 32 + ((kt >> 6) + tb)] >> lr;
                float s = 0.f;
#pragma unroll
                for (int nf = 0; nf < 4; ++nf) {
                    float e = __builtin_amdgcn_exp2f(sc[nf][r]);
                    s += ((mbs >> (nf * 16)) & 1ull) ? e : 0.f;
                }
                lrow[r] += s;
            }
        }
        __syncthreads();
    }

    // ---- reduce over the 16 key-lanes ----
    float inv[4];
#pragma unroll
    for (int r = 0; r < 4; ++r) {
        float l = lrow[r];
        l += __shfl_xor(l, 1, 64);
        l += __shfl_xor(l, 2, 64);
        l += __shfl_xor(l, 4, 64);
        l += __shfl_xor(l, 8, 64);
        inv[r] = 1.0f / l;
    }

    // ---- pass B: pipelined — stage(g+1) issued before stores; counted vmcnt ----
    const size_t obase0 = ((size_t)((b * NUM_HEADS + h) * SEQ) + qblk * 64) * SEQ;
    ATT_STAGE(0)
    asm volatile("s_waitcnt vmcnt(0)" ::: "memory");
    __builtin_amdgcn_s_barrier();
    __builtin_amdgcn_sched_barrier(0);
    for (int g = 0; g < 16; ++g) {
        const int kt = g * 128;
        // compute -> Pb
#pragma unroll
        for (int tb = 0; tb < 2; ++tb) {
            f32x4 sc[4];
#pragma unroll
            for (int nf = 0; nf < 4; ++nf) {
                short8 k0 = K_READ(tb, nf, 0);
                short8 k1 = K_READ(tb, nf, 64);
                f32x4 a = {0.f, 0.f, 0.f, 0.f};
                a = __builtin_amdgcn_mfma_f32_16x16x32_bf16(aq[0], k0, a, 0, 0, 0);
                a = __builtin_amdgcn_mfma_f32_16x16x32_bf16(aq[1], k1, a, 0, 0, 0);
                sc[nf] = a;
            }
#pragma unroll
            for (int r = 0; r < 4; ++r) {
                int q = wq + lk * 4 + r;
                int qloc = w * 16 + lk * 4 + r;
                u64 mbs = Mb[mrow0 + (size_t)q * 32 + ((kt >> 6) + tb)] >> lr;
#pragma unroll
                for (int nf = 0; nf < 4; ++nf) {
                    float p = __builtin_amdgcn_exp2f(sc[nf][r]) * inv[r];
                    Pb[qloc * 132 + tb * 64 + nf * 16 + lr] =
                        ((mbs >> (nf * 16)) & 1ull) ? p : 0.f;
                }
            }
        }
        asm volatile("s_waitcnt lgkmcnt(0)" ::: "memory");  // Ks reads + Pb writes retired
        __builtin_amdgcn_s_barrier();                        // all waves: Ks free, Pb ready
        __builtin_amdgcn_sched_barrier(0);
        if (g < 15) ATT_STAGE(kt + 128)   // issue next-group loads FIRST (4 per wave)
        // copy-out: Pb -> 512B-segment stores (8 per thread), queued behind the loads
#pragma unroll
        for (int gg = 0; gg < 8; ++gg) {
            int row = gg * 8 + (t >> 5);
            int col = (t & 31) * 4;
            *(f32x4*)&out[obase0 + (size_t)row * SEQ + kt + col] = *(f32x4*)&Pb[row * 132 + col];
        }
        if (g < 15) {
            // wait only for the 4 stage loads (oldest); stores drain across the barrier
            asm volatile("s_waitcnt vmcnt(8)" ::: "memory");
        }
        asm volatile("s_waitcnt lgkmcnt(0)" ::: "memory");  // Pb reads retired
        __builtin_amdgcn_s_barrier();                        // Ks ready, Pb free
        __builtin_amdgcn_sched_barrier(0);
    }
#undef ATT_STAGE
#undef K_READ
}

extern "C" void kernel_launch(void* const* d_in, const int* in_sizes, int n_in,
                              void* d_out, int out_size, void* d_ws, size_t ws_size,
                              hipStream_t stream) {
    (void)in_sizes; (void)n_in; (void)out_size; (void)ws_size;
    const float* x = (const float*)d_in[0];
    const int* mask = (const int*)d_in[1];
    const float* Wq = (const float*)d_in[2];
    const float* bq = (const float*)d_in[3];
    const float* Wk = (const float*)d_in[4];
    const float* bk = (const float*)d_in[5];
    float* out = (float*)d_out;

    short* Wt = (short*)d_ws;                           // 1536*768 bf16
    short* Xb = Wt + (size_t)NQK * DM;                  // 4096*768 bf16
    short* QK = Xb + (size_t)BATCH * SEQ * DM;          // 4096*1536 bf16
    u64* Mb = (u64*)(QK + (size_t)BATCH * SEQ * NQK);   // 131072 u64

    prep_kernel<<<dim3(6016), 256, 0, stream>>>(Wq, Wk, x, mask, Wt, Xb, Mb);
    proj_kernel<<<dim3(BATCH * SEQ / 128, NQK / 128), 256, 0, stream>>>(Xb, Wt, bq, bk, QK);
    attn_kernel<<<dim3(768), 256, 0, stream>>>(QK, Mb, out);
}

// Round 20
// 151.079 us; speedup vs baseline: 1.0013x; 1.0013x over previous
//
#include <hip/hip_runtime.h>
#include <stdint.h>

#define NUM_HEADS 12
#define DH 64
#define SEQ 2048
#define BATCH 2
#define DM 768
#define NQK 1536  // Q cols [0,768) | K cols [768,1536)
#define LOG2E 1.44269504088896340736f

typedef short short8 __attribute__((ext_vector_type(8)));
typedef short short4_t __attribute__((ext_vector_type(4)));
typedef float f32x4 __attribute__((ext_vector_type(4)));
typedef unsigned long long u64;

__device__ __forceinline__ short bf16_rne(float f) {
    union { float f; uint32_t u; } v; v.f = f;
    return (short)((v.u + 0x7FFFu + ((v.u >> 16) & 1u)) >> 16);
}

// async global->LDS, 16B per lane; LDS dest = wave-uniform base + lane*16 (linear)
#define GLOAD_LDS(gp, lp)                                                          \
    __builtin_amdgcn_global_load_lds(                                              \
        (const __attribute__((address_space(1))) void*)(gp),                       \
        (__attribute__((address_space(3))) void*)(lp), 16, 0, 0)

// ---------------- Kernel 0: prep (wt | xb | mpack), branch on blockIdx ----------------
__global__ __launch_bounds__(256) void prep_kernel(const float* __restrict__ Wq,
                                                   const float* __restrict__ Wk,
                                                   const float* __restrict__ x,
                                                   const int* __restrict__ mask,
                                                   short* __restrict__ Wt,
                                                   short* __restrict__ Xb,
                                                   u64* __restrict__ Mb) {
    __shared__ float tile[32][33];
    const int bid = blockIdx.x;
    const int t = threadIdx.x;
    if (bid < 1152) {
        int n0 = (bid % 48) * 32;
        int k0 = (bid / 48) * 32;
        int tx = t & 31;
        int ty = t >> 5;
        const float* src = (n0 < DM) ? Wq : Wk;
        int nn0 = (n0 < DM) ? n0 : n0 - DM;
#pragma unroll
        for (int j = 0; j < 4; ++j) {
            int k = ty + 8 * j;
            tile[k][tx] = src[(size_t)(k0 + k) * DM + nn0 + tx];
        }
        __syncthreads();
#pragma unroll
        for (int j = 0; j < 4; ++j) {
            int n = ty + 8 * j;
            Wt[(size_t)(n0 + n) * DM + k0 + tx] = bf16_rne(tile[tx][n]);
        }
    } else if (bid < 1920) {
        // ---- xb: x -> bf16 ----
        size_t base = (size_t)(bid - 1152) * 4096;
#pragma unroll
        for (int j = 0; j < 4; ++j) {
            size_t i = base + (size_t)(t + j * 256) * 4;
            f32x4 v = *(const f32x4*)(x + i);
            short4_t s;
#pragma unroll
            for (int e = 0; e < 4; ++e) s[e] = bf16_rne(v[e]);
            *(short4_t*)(Xb + i) = s;
        }
    } else {
        // ---- mpack ----
        int wid = (bid - 1920) * 4 + (t >> 6);
        int lane = t & 63;
        size_t base = (size_t)wid * 8;
#pragma unroll
        for (int i = 0; i < 8; ++i) {
            size_t w = base + i;
            int v = mask[w * 64 + lane];
            u64 bal = __ballot(v != 0);
            if (lane == 0) Mb[w] = bal;
        }
    }
}

// ---------------- Kernel 1: proj GEMM (128x128, BK=64), global_load_lds staging ----------------
__global__ __launch_bounds__(256) void proj_kernel(const short* __restrict__ Xb,
                                                   const short* __restrict__ Wt,
                                                   const float* __restrict__ bq,
                                                   const float* __restrict__ bk,
                                                   short* __restrict__ QK) {
    __shared__ short As[128 * 64];  // 16 KB
    __shared__ short Bs[128 * 64];  // 16 KB
    const int m0 = blockIdx.x * 128;
    const int n0 = blockIdx.y * 128;
    const int t = threadIdx.x;
    const int lane = t & 63;
    const int w = t >> 6;
    const int wr = w >> 1, wc = w & 1;
    const int lr = lane & 15;
    const int lk = lane >> 4;
    const int crow = lane >> 3;            // row within 8-row chunk
    const int cc = (lane & 7) ^ crow;      // swizzled source 16B-chunk index
    const int xr = (lr & 7) << 4;          // read-side XOR (row&7)<<4 bytes

    f32x4 acc[4][4] = {};

    for (int k0 = 0; k0 < DM; k0 += 64) {
#pragma unroll
        for (int i = 0; i < 4; ++i) {
            int ci = w * 4 + i;            // 16 chunks of 8 rows x 1KB
            int row = ci * 8 + crow;
            GLOAD_LDS(&Xb[(size_t)(m0 + row) * DM + k0 + cc * 8], &As[ci * 512]);
            GLOAD_LDS(&Wt[(size_t)(n0 + row) * DM + k0 + cc * 8], &Bs[ci * 512]);
        }
        __syncthreads();
#pragma unroll
        for (int kk = 0; kk < 2; ++kk) {
            short8 a[4], bfr[4];
#pragma unroll
            for (int m = 0; m < 4; ++m) {
                int row = wr * 64 + m * 16 + lr;
                a[m] = *(short8*)((char*)As + row * 128 + ((kk * 64 + lk * 16) ^ xr));
            }
#pragma unroll
            for (int n = 0; n < 4; ++n) {
                int row = wc * 64 + n * 16 + lr;
                bfr[n] = *(short8*)((char*)Bs + row * 128 + ((kk * 64 + lk * 16) ^ xr));
            }
#pragma unroll
            for (int m = 0; m < 4; ++m)
#pragma unroll
                for (int n = 0; n < 4; ++n)
                    acc[m][n] = __builtin_amdgcn_mfma_f32_16x16x32_bf16(a[m], bfr[n], acc[m][n], 0, 0, 0);
        }
        __syncthreads();
    }

    const int orow = m0 + wr * 64;
    const int ocol = n0 + wc * 64;
#pragma unroll
    for (int m = 0; m < 4; ++m) {
#pragma unroll
        for (int n = 0; n < 4; ++n) {
            int col = ocol + n * 16 + lr;
            float bias = (col < DM) ? bq[col] : bk[col - DM];
            float scale = (col < DM) ? 0.125f * LOG2E : 1.0f;
#pragma unroll
            for (int r = 0; r < 4; ++r) {
                int row = orow + m * 16 + lk * 4 + r;
                QK[(size_t)row * NQK + col] = bf16_rne((acc[m][n][r] + bias) * scale);
            }
        }
    }
}

// ---------------- Kernel 2: attn (R11 + global_load_lds K-staging, swizzled linear Ks) ----------------
__global__ __launch_bounds__(256) void attn_kernel(const short* __restrict__ QK,
                                                   const u64* __restrict__ Mb,
                                                   float* __restrict__ out) {
    __shared__ short Ks[2][64 * 64];   // 16 KB (linear, swizzled)
    __shared__ float Pb[64 * 132];     // 33.8 KB
    const int bid = blockIdx.x;
    const int xcd = bid & 7;
    const int jj = bid >> 3;
    const int bh = xcd * 3 + (jj >> 5);
    const int qblk = jj & 31;
    const int b = bh / NUM_HEADS;
    const int h = bh % NUM_HEADS;
    const int t = threadIdx.x;
    const int lane = t & 63;
    const int w = t >> 6;
    const int lr = lane & 15;
    const int lk = lane >> 4;
    const int wq = qblk * 64 + w * 16;
    const int crow = lane >> 3;            // row within 8-row region
    const int cc = (lane & 7) ^ crow;      // swizzled source chunk
    const int xr = (lr & 7) << 4;          // read-side XOR

    short8 aq[2];
#pragma unroll
    for (int ks = 0; ks < 2; ++ks)
        aq[ks] = *(const short8*)&QK[(size_t)(b * SEQ + wq + lr) * NQK + h * DH + ks * 32 + lk * 8];

    float lrow[4] = {0.f, 0.f, 0.f, 0.f};
    const size_t mrow0 = (size_t)b * SEQ * 32;

    // stage 128 keys: 16 regions of 8 rows x 1KB; wave w handles regions w*4..w*4+3
#define ATT_STAGE(KT)                                                                             \
    {                                                                                             \
        _Pragma("unroll") for (int i = 0; i < 4; ++i) {                                           \
            int ci = w * 4 + i;                                                                   \
            int tile = ci >> 3;                                                                   \
            int reg = ci & 7;                                                                     \
            int row = reg * 8 + crow;                                                             \
            GLOAD_LDS(&QK[(size_t)(b * SEQ + (KT) + tile * 64 + row) * NQK + DM + h * DH +        \
                          cc * 8],                                                                \
                      &Ks[tile][reg * 512]);                                                      \
        }                                                                                         \
    }

#define K_READ(TB, NF, OFS)                                                                       \
    (*(short8*)((char*)&Ks[TB][0] + ((NF) * 16 + lr) * 128 + (((OFS) + lk * 16) ^ xr)))

    // ---- pass A: masked sum of exp2 ----
    for (int kt = 0; kt < SEQ; kt += 128) {
        ATT_STAGE(kt)
        __syncthreads();
#pragma unroll
        for (int tb = 0; tb < 2; ++tb) {
            f32x4 sc[4];
#pragma unroll
            for (int nf = 0; nf < 4; ++nf) {
                short8 k0 = K_READ(tb, nf, 0);
                short8 k1 = K_READ(tb, nf, 64);
                f32x4 a = {0.f, 0.f, 0.f, 0.f};
                a = __builtin_amdgcn_mfma_f32_16x16x32_bf16(aq[0], k0, a, 0, 0, 0);
                a = __builtin_amdgcn_mfma_f32_16x16x32_bf16(aq[1], k1, a, 0, 0, 0);
                sc[nf] = a;
            }
#pragma unroll
            for (int r = 0; r < 4; ++r) {
                int q = wq + lk * 4 + r;
                u64 mbs = Mb[mrow0 + (size_t)q * 32 + ((kt >> 6) + tb)] >> lr;
                float s = 0.f;
#pragma unroll
                for (int nf = 0; nf < 4; ++nf) {
                    float e = __builtin_amdgcn_exp2f(sc[nf][r]);
                    s += ((mbs >> (nf * 16)) & 1ull) ? e : 0.f;
                }
                lrow[r] += s;
            }
        }
        __syncthreads();
    }

    // ---- reduce over the 16 key-lanes ----
    float inv[4];
#pragma unroll
    for (int r = 0; r < 4; ++r) {
        float l = lrow[r];
        l += __shfl_xor(l, 1, 64);
        l += __shfl_xor(l, 2, 64);
        l += __shfl_xor(l, 4, 64);
        l += __shfl_xor(l, 8, 64);
        inv[r] = 1.0f / l;
    }

    // ---- pass B: recompute -> Pb (LDS) -> 512B-segment coalesced stores ----
    const size_t obase0 = ((size_t)((b * NUM_HEADS + h) * SEQ) + qblk * 64) * SEQ;
    for (int kt = 0; kt < SEQ; kt += 128) {
        ATT_STAGE(kt)
        __syncthreads();
#pragma unroll
        for (int tb = 0; tb < 2; ++tb) {
            f32x4 sc[4];
#pragma unroll
            for (int nf = 0; nf < 4; ++nf) {
                short8 k0 = K_READ(tb, nf, 0);
                short8 k1 = K_READ(tb, nf, 64);
                f32x4 a = {0.f, 0.f, 0.f, 0.f};
                a = __builtin_amdgcn_mfma_f32_16x16x32_bf16(aq[0], k0, a, 0, 0, 0);
                a = __builtin_amdgcn_mfma_f32_16x16x32_bf16(aq[1], k1, a, 0, 0, 0);
                sc[nf] = a;
            }
#pragma unroll
            for (int r = 0; r < 4; ++r) {
                int q = wq + lk * 4 + r;
                int qloc = w * 16 + lk * 4 + r;
                u64 mbs = Mb[mrow0 + (size_t)q * 32 + ((kt >> 6) + tb)] >> lr;
#pragma unroll
                for (int nf = 0; nf < 4; ++nf) {
                    float p = __builtin_amdgcn_exp2f(sc[nf][r]) * inv[r];
                    Pb[qloc * 132 + tb * 64 + nf * 16 + lr] =
                        ((mbs >> (nf * 16)) & 1ull) ? p : 0.f;
                }
            }
        }
        __syncthreads();
#pragma unroll
        for (int g = 0; g < 8; ++g) {
            int row = g * 8 + (t >> 5);
            int col = (t & 31) * 4;
            *(f32x4*)&out[obase0 + (size_t)row * SEQ + kt + col] = *(f32x4*)&Pb[row * 132 + col];
        }
    }
#undef ATT_STAGE
#undef K_READ
}

extern "C" void kernel_launch(void* const* d_in, const int* in_sizes, int n_in,
                              void* d_out, int out_size, void* d_ws, size_t ws_size,
                              hipStream_t stream) {
    (void)in_sizes; (void)n_in; (void)out_size; (void)ws_size;
    const float* x = (const float*)d_in[0];
    const int* mask = (const int*)d_in[1];
    const float* Wq = (const float*)d_in[2];
    const float* bq = (const float*)d_in[3];
    const float* Wk = (const float*)d_in[4];
    const float* bk = (const float*)d_in[5];
    float* out = (float*)d_out;

    short* Wt = (short*)d_ws;                           // 1536*768 bf16
    short* Xb = Wt + (size_t)NQK * DM;                  // 4096*768 bf16
    short* QK = Xb + (size_t)BATCH * SEQ * DM;          // 4096*1536 bf16
    u64* Mb = (u64*)(QK + (size_t)BATCH * SEQ * NQK);   // 131072 u64

    prep_kernel<<<dim3(6016), 256, 0, stream>>>(Wq, Wk, x, mask, Wt, Xb, Mb);
    proj_kernel<<<dim3(BATCH * SEQ / 128, NQK / 128), 256, 0, stream>>>(Xb, Wt, bq, bk, QK);
    attn_kernel<<<dim3(768), 256, 0, stream>>>(QK, Mb, out);
}